// Round 1
// baseline (149.684 us; speedup 1.0000x reference)
//
#include <hip/hip_runtime.h>
#include <hip/hip_bf16.h>

// Problem constants (fixed by setup_inputs): B=8, S=4096, D=1024, H=256
#define BQ   8
#define SQ   4096
#define DQ   1024
#define HQ   256
#define MAXC 64
#define MAXL 64
#define MINL 4

typedef short bf16x8 __attribute__((ext_vector_type(8)));
typedef float f32x4  __attribute__((ext_vector_type(4)));

__device__ __forceinline__ short f2b(float f) {
    union { float f; unsigned u; } v; v.f = f;
    unsigned r = v.u + 0x7FFFu + ((v.u >> 16) & 1u);   // RNE to bf16
    return (short)(r >> 16);
}

// ---------------------------------------------------------------------------
// Kernel 0: repack W1 [K=1024][N=256] f32 -> bf16, k-major groups of 8:
// W1s[((k>>3)*256 + n)*8 + (k&7)]  so each MFMA B-fragment is one 16B load.
// ---------------------------------------------------------------------------
__global__ __launch_bounds__(HQ) void prep_w1(const float* __restrict__ W1,
                                              short* __restrict__ W1s) {
    int k = blockIdx.x;          // 0..1023
    int n = threadIdx.x;         // 0..255
    W1s[((size_t)(k >> 3) * HQ + n) * 8 + (k & 7)] = f2b(W1[(size_t)k * HQ + n]);
}

// ---------------------------------------------------------------------------
// Kernel 1: fused boundary predictor.
// Each block: 64 tokens x all 256 hidden units, K-loop over 1024.
// 4 waves; wave w owns columns [w*64, w*64+64). No LDS staging for operands
// (A re-read x4 hits L1/L2; B is 512KB L2-resident).
// Epilogue: +b1, exact GELU, *W2, reduce -> logit -> boundary bit.
// ---------------------------------------------------------------------------
__global__ __launch_bounds__(256) void predictor(
        const float* __restrict__ hid, const short* __restrict__ W1s,
        const float* __restrict__ b1, const float* __restrict__ W2,
        const float* __restrict__ b2, float* __restrict__ bout) {
    const int m0   = blockIdx.x * 64;       // global token base (flat B*S)
    const int lane = threadIdx.x & 63;
    const int w    = threadIdx.x >> 6;      // wave 0..3
    const int l15  = lane & 15;
    const int l4   = lane >> 4;             // 0..3

    f32x4 acc[4][4] = {};                   // [mi][ni], 64 VGPRs

    const float* arow[4];
#pragma unroll
    for (int mi = 0; mi < 4; ++mi)
        arow[mi] = hid + (size_t)(m0 + mi * 16 + l15) * DQ + 8 * l4;

    const short* bbase = W1s + ((size_t)l4 * HQ + (w * 64 + l15)) * 8;

    for (int ks = 0; ks < 32; ++ks) {       // K-step of 32
        const int k0 = ks * 32;
        bf16x8 a[4];
#pragma unroll
        for (int mi = 0; mi < 4; ++mi) {
            f32x4 lo = *(const f32x4*)(arow[mi] + k0);
            f32x4 hi = *(const f32x4*)(arow[mi] + k0 + 4);
            bf16x8 t;
            t[0] = f2b(lo[0]); t[1] = f2b(lo[1]); t[2] = f2b(lo[2]); t[3] = f2b(lo[3]);
            t[4] = f2b(hi[0]); t[5] = f2b(hi[1]); t[6] = f2b(hi[2]); t[7] = f2b(hi[3]);
            a[mi] = t;
        }
        bf16x8 bf[4];
        const short* bp = bbase + (size_t)ks * 4 * HQ * 8;
#pragma unroll
        for (int ni = 0; ni < 4; ++ni)
            bf[ni] = *(const bf16x8*)(bp + ni * 16 * 8);
#pragma unroll
        for (int mi = 0; mi < 4; ++mi)
#pragma unroll
            for (int ni = 0; ni < 4; ++ni)
                acc[mi][ni] = __builtin_amdgcn_mfma_f32_16x16x32_bf16(
                    a[mi], bf[ni], acc[mi][ni], 0, 0, 0);
    }

    // Epilogue: D mapping col = lane&15 (n within 16), row = 4*(lane>>4)+reg.
    __shared__ float part[4][64];
    float b1v[4], w2v[4];
#pragma unroll
    for (int ni = 0; ni < 4; ++ni) {
        int n = w * 64 + ni * 16 + l15;
        b1v[ni] = b1[n];
        w2v[ni] = W2[n];
    }
#pragma unroll
    for (int mi = 0; mi < 4; ++mi) {
#pragma unroll
        for (int r = 0; r < 4; ++r) {
            float p = 0.f;
#pragma unroll
            for (int ni = 0; ni < 4; ++ni) {
                float x = acc[mi][ni][r] + b1v[ni];
                float g = 0.5f * x * (1.0f + erff(x * 0.70710678118f));
                p += g * w2v[ni];
            }
            p += __shfl_xor(p, 1);
            p += __shfl_xor(p, 2);
            p += __shfl_xor(p, 4);
            p += __shfl_xor(p, 8);
            if (l15 == 0) part[w][mi * 16 + 4 * l4 + r] = p;
        }
    }
    __syncthreads();
    if (threadIdx.x < 64) {
        int t = threadIdx.x;
        float logit = part[0][t] + part[1][t] + part[2][t] + part[3][t] + b2[0];
        bout[m0 + t] = (logit > 0.f) ? 1.0f : 0.0f;   // sigmoid(x)>0.5 <=> x>0
    }
}

// ---------------------------------------------------------------------------
// Kernel 2: per-batch serial boundary scan (1 wave per batch).
// Replicates the jax.lax.scan semantics exactly.
// ---------------------------------------------------------------------------
__global__ __launch_bounds__(64) void scan_k(
        const float* __restrict__ bnd, const float* __restrict__ amask,
        int* __restrict__ cs_g, int* __restrict__ cl_g, int* __restrict__ vd_g,
        float* __restrict__ cmask, float* __restrict__ tmask,
        float* __restrict__ nch) {
    const int b = blockIdx.x;
    const int lane = threadIdx.x;

    // valid_len = sum(attention_mask[b])
    float s = 0.f;
    for (int i = lane; i < SQ; i += 64) s += amask[(size_t)b * SQ + i];
#pragma unroll
    for (int d = 32; d >= 1; d >>= 1) s += __shfl_xor(s, d);
    const int vl = (int)s;

    __shared__ int cs[MAXC], cl[MAXC], vd[MAXC];
    cs[lane] = 0; cl[lane] = 0; vd[lane] = 0;
    __syncthreads();

    int start = 0, cidx = 0;
    const float* bb = bnd + (size_t)b * SQ;
    for (int base = 0; base < SQ; base += 64) {
        int t = base + lane;
        bool ib = (bb[t] > 0.5f) || (t == vl - 1);
        unsigned long long mask = __ballot(ib);
        while (mask) {                       // uniform across lanes
            int tt = base + (__ffsll((unsigned long long)mask) - 1);
            mask &= mask - 1;
            int end = tt + 1;
            int clen_ = end - start;
            bool accept = ((clen_ >= MINL) || (cidx == 0)) && (cidx < MAXC);
            if (accept) {
                if (lane == 0) { cs[cidx] = start; cl[cidx] = min(clen_, MAXL); vd[cidx] = 1; }
                ++cidx;
            }
            start = end;
        }
    }
    __syncthreads();

    cs_g[b * MAXC + lane] = cs[lane];
    cl_g[b * MAXC + lane] = cl[lane];
    vd_g[b * MAXC + lane] = vd[lane];
    cmask[b * MAXC + lane] = vd[lane] ? 1.f : 0.f;
    for (int c = 0; c < MAXC; ++c)
        tmask[((size_t)b * MAXC + c) * MAXL + lane] =
            (vd[c] && lane < cl[c]) ? 1.f : 0.f;
    if (lane == 0) nch[b] = (float)max(1, cidx);
}

// ---------------------------------------------------------------------------
// Kernel 3: gather chunks (one block per output row of 1024 f32; zero-fill).
// ---------------------------------------------------------------------------
__global__ __launch_bounds__(256) void gather_k(
        const float* __restrict__ hid, const int* __restrict__ cs_g,
        const int* __restrict__ cl_g, const int* __restrict__ vd_g,
        float* __restrict__ chunks) {
    const int blk = blockIdx.x;              // b*4096 + c*64 + j
    const int j = blk & 63;
    const int c = (blk >> 6) & 63;
    const int b = blk >> 12;

    const int vld = vd_g[b * MAXC + c];
    const int cln = cl_g[b * MAXC + c];
    const int cst = cs_g[b * MAXC + c];

    float4 v = make_float4(0.f, 0.f, 0.f, 0.f);
    if (vld && j < cln) {
        int row = min(cst + j, SQ - 1);      // clip (no-op for valid entries)
        const float* src = hid + ((size_t)b * SQ + row) * DQ;
        v = *(const float4*)(src + threadIdx.x * 4);
    }
    float* dst = chunks + (size_t)blk * DQ;
    *(float4*)(dst + threadIdx.x * 4) = v;
}

// ---------------------------------------------------------------------------
extern "C" void kernel_launch(void* const* d_in, const int* in_sizes, int n_in,
                              void* d_out, int out_size, void* d_ws, size_t ws_size,
                              hipStream_t stream) {
    const float* hid   = (const float*)d_in[0];
    const float* amask = (const float*)d_in[1];
    const float* W1    = (const float*)d_in[2];
    const float* b1    = (const float*)d_in[3];
    const float* W2    = (const float*)d_in[4];
    const float* b2    = (const float*)d_in[5];

    float* out    = (float*)d_out;
    float* chunks = out;                                         // [B,64,64,D]
    float* cmask  = chunks + (size_t)BQ * MAXC * MAXL * DQ;      // [B,64]
    float* tmask  = cmask + BQ * MAXC;                           // [B,64,64]
    float* bout   = tmask + BQ * MAXC * MAXL;                    // [B,S]
    float* nch    = bout + (size_t)BQ * SQ;                      // [B]

    short* W1s = (short*)d_ws;                                   // 512 KB
    int* cs_g = (int*)((char*)d_ws + (size_t)DQ * HQ * sizeof(short));
    int* cl_g = cs_g + BQ * MAXC;
    int* vd_g = cl_g + BQ * MAXC;

    prep_w1<<<DQ, HQ, 0, stream>>>(W1, W1s);
    predictor<<<(BQ * SQ) / 64, 256, 0, stream>>>(hid, W1s, b1, W2, b2, bout);
    scan_k<<<BQ, 64, 0, stream>>>(bout, amask, cs_g, cl_g, vd_g, cmask, tmask, nch);
    gather_k<<<BQ * MAXC * MAXL, 256, 0, stream>>>(hid, cs_g, cl_g, vd_g, chunks);
}

// Round 2
// 145.344 us; speedup vs baseline: 1.0299x; 1.0299x over previous
//
#include <hip/hip_runtime.h>
#include <hip/hip_bf16.h>

// Problem constants (fixed by setup_inputs): B=8, S=4096, D=1024, H=256
#define BQ   8
#define SQ   4096
#define DQ   1024
#define HQ   256
#define MAXC 64
#define MAXL 64
#define MINL 4

typedef short bf16x8 __attribute__((ext_vector_type(8)));
typedef float f32x4  __attribute__((ext_vector_type(4)));
typedef unsigned u32x4 __attribute__((ext_vector_type(4)));

__device__ __forceinline__ short f2b(float f) {
    union { float f; unsigned u; } v; v.f = f;
    unsigned r = v.u + 0x7FFFu + ((v.u >> 16) & 1u);   // RNE to bf16
    return (short)(r >> 16);
}

__device__ __forceinline__ unsigned asu(float f) {
    return __builtin_bit_cast(unsigned, f);
}

// pack hi16(a),hi16(b) -> one dword: result = [b_bf16 | a_bf16<<16]... order:
// low short = a (truncated bf16), high short = b.
__device__ __forceinline__ unsigned pktrunc(float a, float b) {
    return __builtin_amdgcn_perm(asu(b), asu(a), 0x07060302u);
}

// fast GELU: x * sigmoid(1.702 x). Max abs err ~0.02 (logit margin is ~2.3).
__device__ __forceinline__ float fgelu(float x) {
    float e = __expf(-1.702f * x);
    return x * __builtin_amdgcn_rcpf(1.0f + e);
}

// ---------------------------------------------------------------------------
// Kernel 0: repack W1 [K=1024][N=256] f32 -> bf16, k-major groups of 8:
// W1s[((k>>3)*256 + n)*8 + (k&7)]  so each MFMA B-fragment is one 16B load.
// ---------------------------------------------------------------------------
__global__ __launch_bounds__(HQ) void prep_w1(const float* __restrict__ W1,
                                              short* __restrict__ W1s) {
    int k = blockIdx.x;          // 0..1023
    int n = threadIdx.x;         // 0..255
    W1s[((size_t)(k >> 3) * HQ + n) * 8 + (k & 7)] = f2b(W1[(size_t)k * HQ + n]);
}

// ---------------------------------------------------------------------------
// Kernel 1: fused boundary predictor.
// Block = 256 threads (4 waves), 32 tokens. Wave w: row-half r=w&1 (16 rows),
// col-half c=w>>1 (128 cols, ni=0..7). Grid = 1024 blocks -> 4 waves/SIMD.
// A: f32 global loads + v_perm truncation to bf16 (1 inst / 2 elems).
// B: prepacked bf16 fragments, L2-resident (512 KB).
// Epilogue: +b1, fast GELU, *W2, 16-lane shfl reduce -> logit -> bit.
// ---------------------------------------------------------------------------
__global__ __launch_bounds__(256) void predictor(
        const float* __restrict__ hid, const short* __restrict__ W1s,
        const float* __restrict__ b1, const float* __restrict__ W2,
        const float* __restrict__ b2, float* __restrict__ bout) {
    const int m0   = blockIdx.x * 32;       // global token base (flat B*S)
    const int tid  = threadIdx.x;
    const int lane = tid & 63;
    const int w    = tid >> 6;              // wave 0..3
    const int r    = w & 1;                 // row half
    const int c    = w >> 1;                // col half
    const int l15  = lane & 15;
    const int l4   = lane >> 4;             // 0..3

    f32x4 acc[8] = {};                      // [ni], 32 VGPRs

    const float* arow = hid + (size_t)(m0 + r * 16 + l15) * DQ + 8 * l4;
    const short* bp   = W1s + ((size_t)l4 * HQ + (c * 128 + l15)) * 8;

    for (int ks = 0; ks < 32; ++ks) {       // K-step of 32
        f32x4 lo = *(const f32x4*)arow;
        f32x4 hi = *(const f32x4*)(arow + 4);
        arow += 32;

        u32x4 ap;
        ap[0] = pktrunc(lo[0], lo[1]);
        ap[1] = pktrunc(lo[2], lo[3]);
        ap[2] = pktrunc(hi[0], hi[1]);
        ap[3] = pktrunc(hi[2], hi[3]);
        bf16x8 a = __builtin_bit_cast(bf16x8, ap);

        bf16x8 bf[8];
#pragma unroll
        for (int ni = 0; ni < 8; ++ni)
            bf[ni] = *(const bf16x8*)(bp + ni * 16 * 8);
        bp += 4 * HQ * 8;

#pragma unroll
        for (int ni = 0; ni < 8; ++ni)
            acc[ni] = __builtin_amdgcn_mfma_f32_16x16x32_bf16(a, bf[ni], acc[ni], 0, 0, 0);
    }

    // Epilogue. C/D map: col = lane&15, row(token-in-16) = 4*(lane>>4)+reg.
    __shared__ float part[4][16];
    float b1v[8], w2v[8];
#pragma unroll
    for (int ni = 0; ni < 8; ++ni) {
        int n = c * 128 + ni * 16 + l15;
        b1v[ni] = b1[n];
        w2v[ni] = W2[n];
    }
#pragma unroll
    for (int reg = 0; reg < 4; ++reg) {
        float p = 0.f;
#pragma unroll
        for (int ni = 0; ni < 8; ++ni)
            p += fgelu(acc[ni][reg] + b1v[ni]) * w2v[ni];
        p += __shfl_xor(p, 1);
        p += __shfl_xor(p, 2);
        p += __shfl_xor(p, 4);
        p += __shfl_xor(p, 8);
        if (l15 == 0) part[w][4 * l4 + reg] = p;
    }
    __syncthreads();
    if (tid < 32) {
        int rr = tid >> 4, ii = tid & 15;
        float logit = part[rr][ii] + part[rr + 2][ii] + b2[0];
        bout[m0 + tid] = (logit > 0.f) ? 1.0f : 0.0f;   // sigmoid(x)>0.5 <=> x>0
    }
}

// ---------------------------------------------------------------------------
// Kernel 2: per-batch serial boundary scan (1 wave per batch).
// Replicates the jax.lax.scan semantics exactly.
// ---------------------------------------------------------------------------
__global__ __launch_bounds__(64) void scan_k(
        const float* __restrict__ bnd, const float* __restrict__ amask,
        int* __restrict__ cs_g, int* __restrict__ cl_g, int* __restrict__ vd_g,
        float* __restrict__ cmask, float* __restrict__ tmask,
        float* __restrict__ nch) {
    const int b = blockIdx.x;
    const int lane = threadIdx.x;

    // valid_len = sum(attention_mask[b])
    float s = 0.f;
    for (int i = lane; i < SQ; i += 64) s += amask[(size_t)b * SQ + i];
#pragma unroll
    for (int d = 32; d >= 1; d >>= 1) s += __shfl_xor(s, d);
    const int vl = (int)s;

    __shared__ int cs[MAXC], cl[MAXC], vd[MAXC];
    cs[lane] = 0; cl[lane] = 0; vd[lane] = 0;
    __syncthreads();

    int start = 0, cidx = 0;
    const float* bb = bnd + (size_t)b * SQ;
    for (int base = 0; base < SQ; base += 64) {
        int t = base + lane;
        bool ib = (bb[t] > 0.5f) || (t == vl - 1);
        unsigned long long mask = __ballot(ib);
        while (mask) {                       // uniform across lanes
            int tt = base + (__ffsll((unsigned long long)mask) - 1);
            mask &= mask - 1;
            int end = tt + 1;
            int clen_ = end - start;
            bool accept = ((clen_ >= MINL) || (cidx == 0)) && (cidx < MAXC);
            if (accept) {
                if (lane == 0) { cs[cidx] = start; cl[cidx] = min(clen_, MAXL); vd[cidx] = 1; }
                ++cidx;
            }
            start = end;
        }
    }
    __syncthreads();

    cs_g[b * MAXC + lane] = cs[lane];
    cl_g[b * MAXC + lane] = cl[lane];
    vd_g[b * MAXC + lane] = vd[lane];
    cmask[b * MAXC + lane] = vd[lane] ? 1.f : 0.f;
    for (int c = 0; c < MAXC; ++c)
        tmask[((size_t)b * MAXC + c) * MAXL + lane] =
            (vd[c] && lane < cl[c]) ? 1.f : 0.f;
    if (lane == 0) nch[b] = (float)max(1, cidx);
}

// ---------------------------------------------------------------------------
// Kernel 3: gather chunks (one block per output row of 1024 f32; zero-fill).
// ---------------------------------------------------------------------------
__global__ __launch_bounds__(256) void gather_k(
        const float* __restrict__ hid, const int* __restrict__ cs_g,
        const int* __restrict__ cl_g, const int* __restrict__ vd_g,
        float* __restrict__ chunks) {
    const int blk = blockIdx.x;              // b*4096 + c*64 + j
    const int j = blk & 63;
    const int c = (blk >> 6) & 63;
    const int b = blk >> 12;

    const int vld = vd_g[b * MAXC + c];
    const int cln = cl_g[b * MAXC + c];
    const int cst = cs_g[b * MAXC + c];

    float4 v = make_float4(0.f, 0.f, 0.f, 0.f);
    if (vld && j < cln) {
        int row = min(cst + j, SQ - 1);      // clip (no-op for valid entries)
        const float* src = hid + ((size_t)b * SQ + row) * DQ;
        v = *(const float4*)(src + threadIdx.x * 4);
    }
    float* dst = chunks + (size_t)blk * DQ;
    *(float4*)(dst + threadIdx.x * 4) = v;
}

// ---------------------------------------------------------------------------
extern "C" void kernel_launch(void* const* d_in, const int* in_sizes, int n_in,
                              void* d_out, int out_size, void* d_ws, size_t ws_size,
                              hipStream_t stream) {
    const float* hid   = (const float*)d_in[0];
    const float* amask = (const float*)d_in[1];
    const float* W1    = (const float*)d_in[2];
    const float* b1    = (const float*)d_in[3];
    const float* W2    = (const float*)d_in[4];
    const float* b2    = (const float*)d_in[5];

    float* out    = (float*)d_out;
    float* chunks = out;                                         // [B,64,64,D]
    float* cmask  = chunks + (size_t)BQ * MAXC * MAXL * DQ;      // [B,64]
    float* tmask  = cmask + BQ * MAXC;                           // [B,64,64]
    float* bout   = tmask + BQ * MAXC * MAXL;                    // [B,S]
    float* nch    = bout + (size_t)BQ * SQ;                      // [B]

    short* W1s = (short*)d_ws;                                   // 512 KB
    int* cs_g = (int*)((char*)d_ws + (size_t)DQ * HQ * sizeof(short));
    int* cl_g = cs_g + BQ * MAXC;
    int* vd_g = cl_g + BQ * MAXC;

    prep_w1<<<DQ, HQ, 0, stream>>>(W1, W1s);
    predictor<<<(BQ * SQ) / 32, 256, 0, stream>>>(hid, W1s, b1, W2, b2, bout);
    scan_k<<<BQ, 64, 0, stream>>>(bout, amask, cs_g, cl_g, vd_g, cmask, tmask, nch);
    gather_k<<<BQ * MAXC * MAXL, 256, 0, stream>>>(hid, cs_g, cl_g, vd_g, chunks);
}

// Round 3
// 143.586 us; speedup vs baseline: 1.0425x; 1.0122x over previous
//
#include <hip/hip_runtime.h>
#include <hip/hip_bf16.h>

// Problem constants (fixed by setup_inputs): B=8, S=4096, D=1024, H=256
#define BQ   8
#define SQ   4096
#define DQ   1024
#define HQ   256
#define MAXC 64
#define MAXL 64
#define MINL 4

typedef short bf16x8 __attribute__((ext_vector_type(8)));
typedef float f32x4  __attribute__((ext_vector_type(4)));
typedef unsigned u32x4 __attribute__((ext_vector_type(4)));

__device__ __forceinline__ short f2b(float f) {
    union { float f; unsigned u; } v; v.f = f;
    unsigned r = v.u + 0x7FFFu + ((v.u >> 16) & 1u);   // RNE to bf16
    return (short)(r >> 16);
}

__device__ __forceinline__ unsigned asu(float f) {
    return __builtin_bit_cast(unsigned, f);
}

// pack trunc-bf16(a) (low short) and trunc-bf16(b) (high short) in 1 v_perm.
// Rounding mode irrelevant here: logit margin to 0 is >2 (see notes).
__device__ __forceinline__ unsigned pktrunc(float a, float b) {
    return __builtin_amdgcn_perm(asu(b), asu(a), 0x07060302u);
}

// fast GELU: x * sigmoid(1.702 x). Max abs err ~0.02 (logit margin ~2.3).
__device__ __forceinline__ float fgelu(float x) {
    float e = __expf(-1.702f * x);
    return x * __builtin_amdgcn_rcpf(1.0f + e);
}

// ---------------------------------------------------------------------------
// Kernel 0: repack W1 [K=1024][N=256] f32 -> bf16, k-major groups of 8:
// W1s[((k>>3)*256 + n)*8 + (k&7)]  so each MFMA B-fragment is one 16B load.
// ---------------------------------------------------------------------------
__global__ __launch_bounds__(HQ) void prep_w1(const float* __restrict__ W1,
                                              short* __restrict__ W1s) {
    int k = blockIdx.x;          // 0..1023
    int n = threadIdx.x;         // 0..255
    W1s[((size_t)(k >> 3) * HQ + n) * 8 + (k & 7)] = f2b(W1[(size_t)k * HQ + n]);
}

// ---------------------------------------------------------------------------
// Kernel 1: fused boundary predictor.
// Round-1 shape (traffic-optimal): block = 256 thr / 4 waves, 64 tokens.
// Each wave: all 64 rows (mi=0..3) x 64 cols (w*64..+64, ni=0..3).
//   -> B L2-traffic 256 MB, A L2-traffic 536 MB total.
// NEW: explicit register double-buffer. Iteration k's 12 loads were issued
// in iteration k-1, so the wave always has ~12 KB in flight and the compiler
// emits counted vmcnt instead of a per-iter drain (latency hidden in-wave).
// ---------------------------------------------------------------------------
__global__ __launch_bounds__(256, 2) void predictor(
        const float* __restrict__ hid, const short* __restrict__ W1s,
        const float* __restrict__ b1, const float* __restrict__ W2,
        const float* __restrict__ b2, float* __restrict__ bout) {
    const int m0   = blockIdx.x * 64;       // global token base (flat B*S)
    const int tid  = threadIdx.x;
    const int lane = tid & 63;
    const int w    = tid >> 6;              // wave 0..3 (col group)
    const int l15  = lane & 15;
    const int l4   = lane >> 4;             // 0..3 (k-subgroup)

    f32x4 acc[4][4] = {};                   // [mi][ni], 64 VGPRs

    const float* arow[4];
#pragma unroll
    for (int mi = 0; mi < 4; ++mi)
        arow[mi] = hid + (size_t)(m0 + mi * 16 + l15) * DQ + 8 * l4;

    const short* bp = W1s + ((size_t)l4 * HQ + (w * 64 + l15)) * 8;

    // ---- prefetch iteration 0 ----
    f32x4 plo[4], phi[4];
    bf16x8 pb[4];
#pragma unroll
    for (int mi = 0; mi < 4; ++mi) {
        plo[mi] = *(const f32x4*)(arow[mi]);
        phi[mi] = *(const f32x4*)(arow[mi] + 4);
    }
#pragma unroll
    for (int ni = 0; ni < 4; ++ni)
        pb[ni] = *(const bf16x8*)(bp + ni * 16 * 8);

    for (int ks = 0; ks < 32; ++ks) {       // K-step of 32
        // consume previous prefetch
        f32x4 lo[4], hi[4];
        bf16x8 bf[4];
#pragma unroll
        for (int mi = 0; mi < 4; ++mi) { lo[mi] = plo[mi]; hi[mi] = phi[mi]; }
#pragma unroll
        for (int ni = 0; ni < 4; ++ni) bf[ni] = pb[ni];

        // issue next iteration's loads (stay in flight across the MFMAs)
        if (ks < 31) {
            const int k1 = (ks + 1) * 32;
#pragma unroll
            for (int mi = 0; mi < 4; ++mi) {
                plo[mi] = *(const f32x4*)(arow[mi] + k1);
                phi[mi] = *(const f32x4*)(arow[mi] + k1 + 4);
            }
            const short* bpn = bp + (size_t)(ks + 1) * 4 * HQ * 8;
#pragma unroll
            for (int ni = 0; ni < 4; ++ni)
                pb[ni] = *(const bf16x8*)(bpn + ni * 16 * 8);
        }

        // pack f32 -> bf16 (truncation; 1 v_perm per 2 elems)
        bf16x8 a[4];
#pragma unroll
        for (int mi = 0; mi < 4; ++mi) {
            u32x4 ap;
            ap[0] = pktrunc(lo[mi][0], lo[mi][1]);
            ap[1] = pktrunc(lo[mi][2], lo[mi][3]);
            ap[2] = pktrunc(hi[mi][0], hi[mi][1]);
            ap[3] = pktrunc(hi[mi][2], hi[mi][3]);
            a[mi] = __builtin_bit_cast(bf16x8, ap);
        }

#pragma unroll
        for (int mi = 0; mi < 4; ++mi)
#pragma unroll
            for (int ni = 0; ni < 4; ++ni)
                acc[mi][ni] = __builtin_amdgcn_mfma_f32_16x16x32_bf16(
                    a[mi], bf[ni], acc[mi][ni], 0, 0, 0);
    }

    // Epilogue. C/D map: col = lane&15, row(token-in-16) = 4*(lane>>4)+reg.
    __shared__ float part[4][64];
    float b1v[4], w2v[4];
#pragma unroll
    for (int ni = 0; ni < 4; ++ni) {
        int n = w * 64 + ni * 16 + l15;
        b1v[ni] = b1[n];
        w2v[ni] = W2[n];
    }
#pragma unroll
    for (int mi = 0; mi < 4; ++mi) {
#pragma unroll
        for (int r = 0; r < 4; ++r) {
            float p = 0.f;
#pragma unroll
            for (int ni = 0; ni < 4; ++ni)
                p += fgelu(acc[mi][ni][r] + b1v[ni]) * w2v[ni];
            p += __shfl_xor(p, 1);
            p += __shfl_xor(p, 2);
            p += __shfl_xor(p, 4);
            p += __shfl_xor(p, 8);
            if (l15 == 0) part[w][mi * 16 + 4 * l4 + r] = p;
        }
    }
    __syncthreads();
    if (tid < 64) {
        float logit = part[0][tid] + part[1][tid] + part[2][tid] + part[3][tid] + b2[0];
        bout[m0 + tid] = (logit > 0.f) ? 1.0f : 0.0f;   // sigmoid(x)>0.5 <=> x>0
    }
}

// ---------------------------------------------------------------------------
// Kernel 2: per-batch serial boundary scan (1 wave per batch).
// Replicates the jax.lax.scan semantics exactly.
// ---------------------------------------------------------------------------
__global__ __launch_bounds__(64) void scan_k(
        const float* __restrict__ bnd, const float* __restrict__ amask,
        int* __restrict__ cs_g, int* __restrict__ cl_g, int* __restrict__ vd_g,
        float* __restrict__ cmask, float* __restrict__ tmask,
        float* __restrict__ nch) {
    const int b = blockIdx.x;
    const int lane = threadIdx.x;

    // valid_len = sum(attention_mask[b])
    float s = 0.f;
    for (int i = lane; i < SQ; i += 64) s += amask[(size_t)b * SQ + i];
#pragma unroll
    for (int d = 32; d >= 1; d >>= 1) s += __shfl_xor(s, d);
    const int vl = (int)s;

    __shared__ int cs[MAXC], cl[MAXC], vd[MAXC];
    cs[lane] = 0; cl[lane] = 0; vd[lane] = 0;
    __syncthreads();

    int start = 0, cidx = 0;
    const float* bb = bnd + (size_t)b * SQ;
    for (int base = 0; base < SQ; base += 64) {
        int t = base + lane;
        bool ib = (bb[t] > 0.5f) || (t == vl - 1);
        unsigned long long mask = __ballot(ib);
        while (mask) {                       // uniform across lanes
            int tt = base + (__ffsll((unsigned long long)mask) - 1);
            mask &= mask - 1;
            int end = tt + 1;
            int clen_ = end - start;
            bool accept = ((clen_ >= MINL) || (cidx == 0)) && (cidx < MAXC);
            if (accept) {
                if (lane == 0) { cs[cidx] = start; cl[cidx] = min(clen_, MAXL); vd[cidx] = 1; }
                ++cidx;
            }
            start = end;
        }
    }
    __syncthreads();

    cs_g[b * MAXC + lane] = cs[lane];
    cl_g[b * MAXC + lane] = cl[lane];
    vd_g[b * MAXC + lane] = vd[lane];
    cmask[b * MAXC + lane] = vd[lane] ? 1.f : 0.f;
    for (int c = 0; c < MAXC; ++c)
        tmask[((size_t)b * MAXC + c) * MAXL + lane] =
            (vd[c] && lane < cl[c]) ? 1.f : 0.f;
    if (lane == 0) nch[b] = (float)max(1, cidx);
}

// ---------------------------------------------------------------------------
// Kernel 3: gather chunks (one block per output row of 1024 f32; zero-fill).
// ---------------------------------------------------------------------------
__global__ __launch_bounds__(256) void gather_k(
        const float* __restrict__ hid, const int* __restrict__ cs_g,
        const int* __restrict__ cl_g, const int* __restrict__ vd_g,
        float* __restrict__ chunks) {
    const int blk = blockIdx.x;              // b*4096 + c*64 + j
    const int j = blk & 63;
    const int c = (blk >> 6) & 63;
    const int b = blk >> 12;

    const int vld = vd_g[b * MAXC + c];
    const int cln = cl_g[b * MAXC + c];
    const int cst = cs_g[b * MAXC + c];

    float4 v = make_float4(0.f, 0.f, 0.f, 0.f);
    if (vld && j < cln) {
        int row = min(cst + j, SQ - 1);      // clip (no-op for valid entries)
        const float* src = hid + ((size_t)b * SQ + row) * DQ;
        v = *(const float4*)(src + threadIdx.x * 4);
    }
    float* dst = chunks + (size_t)blk * DQ;
    *(float4*)(dst + threadIdx.x * 4) = v;
}

// ---------------------------------------------------------------------------
extern "C" void kernel_launch(void* const* d_in, const int* in_sizes, int n_in,
                              void* d_out, int out_size, void* d_ws, size_t ws_size,
                              hipStream_t stream) {
    const float* hid   = (const float*)d_in[0];
    const float* amask = (const float*)d_in[1];
    const float* W1    = (const float*)d_in[2];
    const float* b1    = (const float*)d_in[3];
    const float* W2    = (const float*)d_in[4];
    const float* b2    = (const float*)d_in[5];

    float* out    = (float*)d_out;
    float* chunks = out;                                         // [B,64,64,D]
    float* cmask  = chunks + (size_t)BQ * MAXC * MAXL * DQ;      // [B,64]
    float* tmask  = cmask + BQ * MAXC;                           // [B,64,64]
    float* bout   = tmask + BQ * MAXC * MAXL;                    // [B,S]
    float* nch    = bout + (size_t)BQ * SQ;                      // [B]

    short* W1s = (short*)d_ws;                                   // 512 KB
    int* cs_g = (int*)((char*)d_ws + (size_t)DQ * HQ * sizeof(short));
    int* cl_g = cs_g + BQ * MAXC;
    int* vd_g = cl_g + BQ * MAXC;

    prep_w1<<<DQ, HQ, 0, stream>>>(W1, W1s);
    predictor<<<(BQ * SQ) / 64, 256, 0, stream>>>(hid, W1s, b1, W2, b2, bout);
    scan_k<<<BQ, 64, 0, stream>>>(bout, amask, cs_g, cl_g, vd_g, cmask, tmask, nch);
    gather_k<<<BQ * MAXC * MAXL, 256, 0, stream>>>(hid, cs_g, cl_g, vd_g, chunks);
}

// Round 4
// 122.421 us; speedup vs baseline: 1.2227x; 1.1729x over previous
//
#include <hip/hip_runtime.h>
#include <hip/hip_bf16.h>

// Problem constants (fixed by setup_inputs): B=8, S=4096, D=1024, H=256
#define BQ   8
#define SQ   4096
#define DQ   1024
#define HQ   256
#define MAXC 64
#define MAXL 64
#define MINL 4
#define TQ   32     // tokens per predictor block

typedef short bf16x8 __attribute__((ext_vector_type(8)));
typedef float f32x4  __attribute__((ext_vector_type(4)));
typedef unsigned u32x2 __attribute__((ext_vector_type(2)));

__device__ __forceinline__ short f2b(float f) {
    union { float f; unsigned u; } v; v.f = f;
    unsigned r = v.u + 0x7FFFu + ((v.u >> 16) & 1u);   // RNE to bf16
    return (short)(r >> 16);
}

__device__ __forceinline__ unsigned asu(float f) {
    return __builtin_bit_cast(unsigned, f);
}

// pack trunc-bf16(a) (low short), trunc-bf16(b) (high short) in one v_perm.
// Truncation is fine: logit ~ N(-3, 0.16); margin to the 0 threshold > 2.
__device__ __forceinline__ unsigned pktrunc(float a, float b) {
    return __builtin_amdgcn_perm(asu(b), asu(a), 0x07060302u);
}

// fast GELU: x * sigmoid(1.702 x). Max abs err ~0.02 (logit margin ~2.3).
__device__ __forceinline__ float fgelu(float x) {
    float e = __expf(-1.702f * x);
    return x * __builtin_amdgcn_rcpf(1.0f + e);
}

// ---------------------------------------------------------------------------
// Kernel 0: repack W1 [K=1024][N=256] f32 -> bf16, k-major groups of 8:
// W1s[((k>>3)*256 + n)*8 + (k&7)]  so each MFMA B-fragment is one 16B load.
// ---------------------------------------------------------------------------
__global__ __launch_bounds__(HQ) void prep_w1(const float* __restrict__ W1,
                                              short* __restrict__ W1s) {
    int k = blockIdx.x;          // 0..1023
    int n = threadIdx.x;         // 0..255
    W1s[((size_t)(k >> 3) * HQ + n) * 8 + (k & 7)] = f2b(W1[(size_t)k * HQ + n]);
}

// ---------------------------------------------------------------------------
// Kernel 1: fused boundary predictor, streaming-first design.
// Block = 256 thr (4 waves), 32 consecutive tokens = ONE CONTIGUOUS 128 KB
// region of hid. Stage it memcpy-style (thread t <-> byte t*16 of each 4 KB
// row: coalesced, uniform L2-channel coverage), convert f32->bf16 in regs,
// ds_write into a 64 KB LDS tile with XOR swizzle ((row&7)<<4). One barrier.
// Then 32 MFMA K-steps: A-fragments from LDS (2-way conflicts = free),
// B prepacked bf16 from L2 with 1-step register prefetch.
// Wave w: all 32 rows (mi=0,1) x cols [w*64, w*64+64) (ni=0..3).
// ---------------------------------------------------------------------------
__global__ __launch_bounds__(256) void predictor(
        const float* __restrict__ hid, const short* __restrict__ W1s,
        const float* __restrict__ b1, const float* __restrict__ W2,
        const float* __restrict__ b2, float* __restrict__ bout) {
    const int m0   = blockIdx.x * TQ;       // global token base (flat B*S)
    const int tid  = threadIdx.x;
    const int lane = tid & 63;
    const int w    = tid >> 6;              // wave 0..3 (col group)
    const int l15  = lane & 15;
    const int l4   = lane >> 4;             // 0..3 (k-subgroup)

    __shared__ short As[TQ * DQ];           // 64 KB, swizzled bf16 tile
    __shared__ float part[4][TQ];

    // ---- stage: 32 rows x 4 KB, fully coalesced, batches of 8 rows ----
    const float* src = hid + (size_t)m0 * DQ + tid * 4;
    for (int i0 = 0; i0 < TQ; i0 += 8) {
        f32x4 v[8];
#pragma unroll
        for (int i = 0; i < 8; ++i)
            v[i] = *(const f32x4*)(src + (size_t)(i0 + i) * DQ);
#pragma unroll
        for (int i = 0; i < 8; ++i) {
            int row = i0 + i;
            u32x2 dv;
            dv[0] = pktrunc(v[i][0], v[i][1]);
            dv[1] = pktrunc(v[i][2], v[i][3]);
            unsigned byte = (unsigned)(row * 2048 + tid * 8) ^ ((row & 7) << 4);
            *(u32x2*)((char*)As + byte) = dv;   // ds_write_b64
        }
    }
    __syncthreads();

    // ---- compute: 32 K-steps from LDS + L2-resident B ----
    f32x4 acc[2][4] = {};                   // [mi][ni]
    const short* bp = W1s + ((size_t)l4 * HQ + (w * 64 + l15)) * 8;

    bf16x8 pb[4];
#pragma unroll
    for (int ni = 0; ni < 4; ++ni)
        pb[ni] = *(const bf16x8*)(bp + ni * 16 * 8);

    for (int ks = 0; ks < 32; ++ks) {
        bf16x8 bfr[4];
#pragma unroll
        for (int ni = 0; ni < 4; ++ni) bfr[ni] = pb[ni];
        if (ks < 31) {
            const short* bpn = bp + (size_t)(ks + 1) * 4 * HQ * 8;
#pragma unroll
            for (int ni = 0; ni < 4; ++ni)
                pb[ni] = *(const bf16x8*)(bpn + ni * 16 * 8);
        }

        bf16x8 a[2];
#pragma unroll
        for (int mi = 0; mi < 2; ++mi) {
            int row = mi * 16 + l15;
            unsigned byte = (unsigned)(row * 2048 + ks * 64 + l4 * 16)
                          ^ ((row & 7) << 4);
            a[mi] = *(const bf16x8*)((const char*)As + byte);  // ds_read_b128
        }

#pragma unroll
        for (int mi = 0; mi < 2; ++mi)
#pragma unroll
            for (int ni = 0; ni < 4; ++ni)
                acc[mi][ni] = __builtin_amdgcn_mfma_f32_16x16x32_bf16(
                    a[mi], bfr[ni], acc[mi][ni], 0, 0, 0);
    }

    // ---- epilogue. C/D map: col = lane&15, row-in-16 = 4*(lane>>4)+reg ----
    float b1v[4], w2v[4];
#pragma unroll
    for (int ni = 0; ni < 4; ++ni) {
        int n = w * 64 + ni * 16 + l15;
        b1v[ni] = b1[n];
        w2v[ni] = W2[n];
    }
#pragma unroll
    for (int mi = 0; mi < 2; ++mi) {
#pragma unroll
        for (int r = 0; r < 4; ++r) {
            float p = 0.f;
#pragma unroll
            for (int ni = 0; ni < 4; ++ni)
                p += fgelu(acc[mi][ni][r] + b1v[ni]) * w2v[ni];
            p += __shfl_xor(p, 1);
            p += __shfl_xor(p, 2);
            p += __shfl_xor(p, 4);
            p += __shfl_xor(p, 8);
            if (l15 == 0) part[w][mi * 16 + 4 * l4 + r] = p;
        }
    }
    __syncthreads();
    if (tid < TQ) {
        float logit = part[0][tid] + part[1][tid] + part[2][tid] + part[3][tid] + b2[0];
        bout[m0 + tid] = (logit > 0.f) ? 1.0f : 0.0f;   // sigmoid(x)>0.5 <=> x>0
    }
}

// ---------------------------------------------------------------------------
// Kernel 2: per-batch serial boundary scan (1 wave per batch).
// Replicates the jax.lax.scan semantics exactly.
// ---------------------------------------------------------------------------
__global__ __launch_bounds__(64) void scan_k(
        const float* __restrict__ bnd, const float* __restrict__ amask,
        int* __restrict__ cs_g, int* __restrict__ cl_g, int* __restrict__ vd_g,
        float* __restrict__ cmask, float* __restrict__ tmask,
        float* __restrict__ nch) {
    const int b = blockIdx.x;
    const int lane = threadIdx.x;

    // valid_len = sum(attention_mask[b])
    float s = 0.f;
    for (int i = lane; i < SQ; i += 64) s += amask[(size_t)b * SQ + i];
#pragma unroll
    for (int d = 32; d >= 1; d >>= 1) s += __shfl_xor(s, d);
    const int vl = (int)s;

    __shared__ int cs[MAXC], cl[MAXC], vd[MAXC];
    cs[lane] = 0; cl[lane] = 0; vd[lane] = 0;
    __syncthreads();

    int start = 0, cidx = 0;
    const float* bb = bnd + (size_t)b * SQ;
    for (int base = 0; base < SQ; base += 64) {
        int t = base + lane;
        bool ib = (bb[t] > 0.5f) || (t == vl - 1);
        unsigned long long mask = __ballot(ib);
        while (mask) {                       // uniform across lanes
            int tt = base + (__ffsll((unsigned long long)mask) - 1);
            mask &= mask - 1;
            int end = tt + 1;
            int clen_ = end - start;
            bool accept = ((clen_ >= MINL) || (cidx == 0)) && (cidx < MAXC);
            if (accept) {
                if (lane == 0) { cs[cidx] = start; cl[cidx] = min(clen_, MAXL); vd[cidx] = 1; }
                ++cidx;
            }
            start = end;
        }
    }
    __syncthreads();

    cs_g[b * MAXC + lane] = cs[lane];
    cl_g[b * MAXC + lane] = cl[lane];
    vd_g[b * MAXC + lane] = vd[lane];
    cmask[b * MAXC + lane] = vd[lane] ? 1.f : 0.f;
    for (int c = 0; c < MAXC; ++c)
        tmask[((size_t)b * MAXC + c) * MAXL + lane] =
            (vd[c] && lane < cl[c]) ? 1.f : 0.f;
    if (lane == 0) nch[b] = (float)max(1, cidx);
}

// ---------------------------------------------------------------------------
// Kernel 3: gather chunks. Block = (b, c, 16-row slice): 2048 blocks, each
// streams 64 KB of output (16 rows x 4 KB), zero-filling invalid entries.
// Per-thread 16 independent 16B stores -> deep store pipeline.
// ---------------------------------------------------------------------------
__global__ __launch_bounds__(256) void gather_k(
        const float* __restrict__ hid, const int* __restrict__ cs_g,
        const int* __restrict__ cl_g, const int* __restrict__ vd_g,
        float* __restrict__ chunks) {
    const int blk = blockIdx.x;              // b*256 + c*4 + slice
    const int j0 = (blk & 3) * 16;
    const int c  = (blk >> 2) & 63;
    const int b  = blk >> 8;

    const int vld = vd_g[b * MAXC + c];
    const int cln = cl_g[b * MAXC + c];
    const int cst = cs_g[b * MAXC + c];

    const float* srcb = hid + (size_t)b * SQ * DQ + threadIdx.x * 4;
    float* dst = chunks + (((size_t)(b * MAXC + c)) * MAXL + j0) * DQ + threadIdx.x * 4;

#pragma unroll 4
    for (int jj = 0; jj < 16; ++jj) {
        int j = j0 + jj;
        f32x4 v = {0.f, 0.f, 0.f, 0.f};
        if (vld && j < cln) {
            int row = min(cst + j, SQ - 1);
            v = *(const f32x4*)(srcb + (size_t)row * DQ);
        }
        *(f32x4*)(dst + (size_t)jj * DQ) = v;
    }
}

// ---------------------------------------------------------------------------
extern "C" void kernel_launch(void* const* d_in, const int* in_sizes, int n_in,
                              void* d_out, int out_size, void* d_ws, size_t ws_size,
                              hipStream_t stream) {
    const float* hid   = (const float*)d_in[0];
    const float* amask = (const float*)d_in[1];
    const float* W1    = (const float*)d_in[2];
    const float* b1    = (const float*)d_in[3];
    const float* W2    = (const float*)d_in[4];
    const float* b2    = (const float*)d_in[5];

    float* out    = (float*)d_out;
    float* chunks = out;                                         // [B,64,64,D]
    float* cmask  = chunks + (size_t)BQ * MAXC * MAXL * DQ;      // [B,64]
    float* tmask  = cmask + BQ * MAXC;                           // [B,64,64]
    float* bout   = tmask + BQ * MAXC * MAXL;                    // [B,S]
    float* nch    = bout + (size_t)BQ * SQ;                      // [B]

    short* W1s = (short*)d_ws;                                   // 512 KB
    int* cs_g = (int*)((char*)d_ws + (size_t)DQ * HQ * sizeof(short));
    int* cl_g = cs_g + BQ * MAXC;
    int* vd_g = cl_g + BQ * MAXC;

    prep_w1<<<DQ, HQ, 0, stream>>>(W1, W1s);
    predictor<<<(BQ * SQ) / TQ, 256, 0, stream>>>(hid, W1s, b1, W2, b2, bout);
    scan_k<<<BQ, 64, 0, stream>>>(bout, amask, cs_g, cl_g, vd_g, cmask, tmask, nch);
    gather_k<<<BQ * MAXC * 4, 256, 0, stream>>>(hid, cs_g, cl_g, vd_g, chunks);
}